// Round 6
// baseline (353.338 us; speedup 1.0000x reference)
//
#include <hip/hip_runtime.h>
#include <math.h>

#define Bn 4
#define Nn 2048
#define Hn 8
#define HDn 32
#define Dn 256
#define MHALF 1024  // m-split: 2 partials merged in oproj
#define NT 16       // q-rows per attn block: 1024 blocks -> 4 blocks/CU

typedef _Float16 h1;
typedef __attribute__((ext_vector_type(8))) _Float16 h8;
typedef __attribute__((ext_vector_type(4))) float fx4;

#define QSCALE 0.35355339059327373f
// |S_raw| <= HD = 32, |S_raw*QSCALE*topo| <= 11.32 -> fixed softmax shift safe:
// p = e^{S-4} in [2.2e-7, 1503] -- fits f16, no running max needed.
#define SOFTMAX_SHIFT 4.0f

// ---------------------------------------------------------------------------
// Kernel 0: W -> f16 transpose via LDS tiles (coalesced both sides)
// ---------------------------------------------------------------------------
__global__ __launch_bounds__(256) void cvtW_kernel(
    const float* __restrict__ Wq, const float* __restrict__ Wk,
    const float* __restrict__ Wv, h1* __restrict__ WT)
{
    __shared__ float tw[64][65];
    const int w = blockIdx.z;
    const int d0 = blockIdx.y * 64, o0 = blockIdx.x * 64;
    const float* W = (w == 0) ? Wq : (w == 1) ? Wk : Wv;
    const int rr = threadIdx.x >> 6, cc = threadIdx.x & 63;
#pragma unroll
    for (int i = 0; i < 16; ++i)
        tw[rr + i * 4][cc] = W[(size_t)(d0 + rr + i * 4) * 256 + o0 + cc];
    __syncthreads();
#pragma unroll
    for (int i = 0; i < 16; ++i) {
        const int row = rr + i * 4;
        WT[(size_t)w * 65536 + (size_t)(o0 + row) * 256 + d0 + cc] = (h1)tw[cc][row];
    }
}

// ---------------------------------------------------------------------------
// Kernel 1: QKV projection via f16 MFMA (x split hi/lo for ~f32 accuracy).
// ---------------------------------------------------------------------------
__global__ __launch_bounds__(256) __attribute__((amdgpu_waves_per_eu(4, 4)))
void proj_kernel(
    const float* __restrict__ x, const h1* __restrict__ WT,
    const float* __restrict__ bq, const float* __restrict__ bk,
    const float* __restrict__ bv,
    h1* __restrict__ fq, h1* __restrict__ fk, h1* __restrict__ vT)
{
    __shared__ __align__(16) h1 fbuf[64][264];
    const int tid = threadIdx.x;
    const int w = tid >> 6;
    const int lane = tid & 63;
    const int quad = lane >> 4;
    const int l15 = lane & 15;
    const int wsel = blockIdx.y >> 1;
    const int hg = blockIdx.y & 1;
    const int r0 = blockIdx.x * 64;
    const int arow = r0 + w * 16 + l15;
    const int b = r0 >> 11, n0 = r0 & (Nn - 1);

    const h1* WTw = WT + (size_t)wsel * 65536;
    fx4 acc[8];
#pragma unroll
    for (int ct = 0; ct < 8; ++ct) acc[ct] = (fx4){0.f, 0.f, 0.f, 0.f};

    for (int ks = 0; ks < 8; ++ks) {
        float xv[8];
        *(float4*)&xv[0] = *(const float4*)&x[(size_t)arow * 256 + ks * 32 + quad * 8];
        *(float4*)&xv[4] = *(const float4*)&x[(size_t)arow * 256 + ks * 32 + quad * 8 + 4];
        h8 Ahi, Alo;
#pragma unroll
        for (int j = 0; j < 8; ++j) {
            const h1 hi = (h1)xv[j];
            Ahi[j] = hi;
            Alo[j] = (h1)(xv[j] - (float)hi);
        }
        h8 Bf[8];
#pragma unroll
        for (int ct = 0; ct < 8; ++ct)
            Bf[ct] = *(const h8*)&WTw[(size_t)(hg * 128 + ct * 16 + l15) * 256 + ks * 32 + quad * 8];
#pragma unroll
        for (int ct = 0; ct < 8; ++ct) {
            acc[ct] = __builtin_amdgcn_mfma_f32_16x16x32_f16(Ahi, Bf[ct], acc[ct], 0, 0, 0);
            acc[ct] = __builtin_amdgcn_mfma_f32_16x16x32_f16(Alo, Bf[ct], acc[ct], 0, 0, 0);
        }
    }

    const float* bias = (wsel == 0) ? bq : (wsel == 1) ? bk : bv;

    if (wsel < 2) {
        h1* f = (wsel == 0) ? fq : fk;
#pragma unroll
        for (int ct = 0; ct < 8; ++ct) {
            const int c = ct * 16 + l15;
            const float bb = bias[hg * 128 + c];
            const int hh4 = c >> 5, dd = c & 31;
#pragma unroll
            for (int r = 0; r < 4; ++r) {
                const float val = acc[ct][r] + bb;
                const float sv = __sinf(val), cv = __cosf(val);
                h1* fp = &fbuf[w * 16 + quad * 4 + r][hh4 * 64 + dd];
                fp[0]  = (h1)cv;
                fp[32] = (h1)sv;
            }
        }
        __syncthreads();
        const int row = tid >> 2, q4 = tid & 3;
#pragma unroll
        for (int g = 0; g < 8; ++g) {
            const int chunk = q4 + g * 4;
            const int hh4 = chunk >> 3, within = chunk & 7;
            const h8 val = *(const h8*)&fbuf[row][hh4 * 64 + within * 8];
            const int head = hg * 4 + hh4;
            *(h8*)&f[((size_t)(b * Hn + head) * Nn + n0 + row) * 64 + within * 8] = val;
        }
    } else {
        h1 (*vst)[132] = (h1(*)[132])fbuf;
#pragma unroll
        for (int ct = 0; ct < 8; ++ct) {
            const int c = ct * 16 + l15;
            const float bb = bias[hg * 128 + c];
#pragma unroll
            for (int r = 0; r < 4; ++r)
                vst[w * 16 + quad * 4 + r][c] = (h1)(acc[ct][r] + bb);
        }
        __syncthreads();
        const int c2 = tid & 127, half = tid >> 7;
        const int head = hg * 4 + (c2 >> 5), dd = c2 & 31;
        h1* vp = vT + ((size_t)((b * Hn + head) * HDn + dd)) * Nn + n0;
#pragma unroll
        for (int g = 0; g < 4; ++g) {
            const int gg = half * 4 + g;
            h8 pk;
#pragma unroll
            for (int j = 0; j < 8; ++j) pk[j] = vst[gg * 8 + j][c2];
            *(h8*)(vp + gg * 8) = pk;
        }
    }
}

// ---------------------------------------------------------------------------
// Kernel 2: fused attention. Block = 512 thr = 8 waves = ALL 8 heads of one
// (b, NT=16 q-rows, m-half). Grid 1024 blocks = 4 blocks/CU.
//
// Ledger: r9/r12 falsified K/V load latency (clean prefetch, no spill ->
// slower). r10 falsified barrier count + bank conflicts. r12 falsified
// scratch as the cost. Still standing: LOCKSTEP TLP-starvation -- with 2
// barrier-synced blocks/CU every resident wave stalls in the same phase.
// r8 tried 4 blocks/CU but launch_bounds(512,8) forced VGPR=32 ->
// load-use serialization swamped the occupancy gain (confounded).
//
// r13 = r8's exact passing kernel with ONE change: __launch_bounds__(512,4)
// -> 64-VGPR budget. NT=16 state (~54 regs) fits without spill or
// serialization. 4 INDEPENDENT blocks/CU with independent barriers
// de-phase naturally: one block's exp/VALU phase fills another's load
// stall. Verification counters: VGPR 52-64, WRITE_SIZE ~16896 KB (no
// scratch), Occupancy >= 70%.
// Fixed-shift softmax: no reductions in the loop.
// ---------------------------------------------------------------------------
__global__ __launch_bounds__(512, 4) void attn_kernel(
    const h1* __restrict__ fq, const h1* __restrict__ fk, const h1* __restrict__ vT,
    const float* __restrict__ topo, float* __restrict__ pacc, float* __restrict__ pl)
{
    __shared__ __align__(16) h1 Pw[8][NT][40];   // 10.2 KB per-wave P buffers
    __shared__ float tbuf[2][NT][33];            // 4.2 KB topo double buffer

    const int b = blockIdx.y;
    const int mh = blockIdx.z;
    const int n0 = blockIdx.x * NT;
    const int tid = threadIdx.x;
    const int w = tid >> 6;        // wave id = head
    const int h = w;
    const int lane = tid & 63;
    const int quad = lane >> 4;
    const int l15 = lane & 15;

    const h1* qfh = fq + (size_t)(b * Hn + h) * Nn * 64;
    const h1* kfh = fk + (size_t)(b * Hn + h) * Nn * 64;
    const h1* vTh = vT + (size_t)(b * Hn + h) * HDn * Nn;

    // topo cooperative-load mapping: thread -> (row, col); 16x32 f32 tile
    const int trow = tid >> 5, tcol = tid & 31;
    const float* tpg = topo + (size_t)b * Nn * Nn + (size_t)(n0 + trow) * Nn + tcol;

    h8 qfr[2];
#pragma unroll
    for (int ks = 0; ks < 2; ++ks)
        qfr[ks] = *(const h8*)(qfh + (size_t)(n0 + l15) * 64 + ks * 32 + quad * 8);

    fx4 acc[2];
    float lsum[4];
#pragma unroll
    for (int ds = 0; ds < 2; ++ds) acc[ds] = (fx4){0.f, 0.f, 0.f, 0.f};
#pragma unroll
    for (int r = 0; r < 4; ++r) lsum[r] = 0.f;

    const int mbase = mh * MHALF;
    const fx4 z4 = {0.f, 0.f, 0.f, 0.f};

    float rt = tpg[mbase];   // prefetch tile 0

    for (int it = 0; it < MHALF / 32; ++it) {
        const int m0 = mbase + it * 32;
        const int cur = it & 1;

        // commit prefetched topo tile to LDS, issue next tile's load
        tbuf[cur][trow][tcol] = rt;
        if (it < MHALF / 32 - 1) rt = tpg[m0 + 32];
        // raw barrier: waits own LDS writes only; global prefetch stays in flight
        __asm__ volatile("s_waitcnt lgkmcnt(0)\n\ts_barrier" ::: "memory");

        // K fragments + V fragments (per-head, L2-served)
        h8 kfr[2][2];
#pragma unroll
        for (int ms = 0; ms < 2; ++ms)
#pragma unroll
            for (int ks = 0; ks < 2; ++ks)
                kfr[ms][ks] = *(const h8*)(kfh + (size_t)(m0 + ms * 16 + l15) * 64 + ks * 32 + quad * 8);
        h8 bV[2];
#pragma unroll
        for (int ds = 0; ds < 2; ++ds)
            bV[ds] = *(const h8*)(vTh + (size_t)(ds * 16 + l15) * Nn + m0 + quad * 8);

        // S = Qf @ Kf^T
        fx4 S[2];
#pragma unroll
        for (int ms = 0; ms < 2; ++ms) {
            fx4 tmp = __builtin_amdgcn_mfma_f32_16x16x32_f16(qfr[0], kfr[ms][0], z4, 0, 0, 0);
            S[ms] = __builtin_amdgcn_mfma_f32_16x16x32_f16(qfr[1], kfr[ms][1], tmp, 0, 0, 0);
        }

        // p = e^{S*topo*QSCALE - 4}; topo from LDS
#pragma unroll
        for (int ms = 0; ms < 2; ++ms)
#pragma unroll
            for (int r = 0; r < 4; ++r) {
                const float tv = tbuf[cur][quad * 4 + r][ms * 16 + l15];
                const float p = __expf(fmaf(S[ms][r] * tv, QSCALE, -SOFTMAX_SHIFT));
                lsum[r] += p;
                Pw[w][quad * 4 + r][ms * 16 + l15] = (h1)p;
            }
        __asm__ volatile("s_waitcnt lgkmcnt(0)" ::: "memory");

        // PV
        h8 aP = *(const h8*)&Pw[w][l15][quad * 8];
#pragma unroll
        for (int ds = 0; ds < 2; ++ds)
            acc[ds] = __builtin_amdgcn_mfma_f32_16x16x32_f16(aP, bV[ds], acc[ds], 0, 0, 0);
    }

    // epilogue: reduce l across the 16 col-lanes, write partials
#pragma unroll
    for (int r = 0; r < 4; ++r)
#pragma unroll
        for (int off = 1; off <= 8; off <<= 1)
            lsum[r] += __shfl_xor(lsum[r], off);

    float* paccm = pacc + (size_t)mh * Bn * Nn * Dn;
    float* plm   = pl   + (size_t)mh * Bn * Nn * Hn;
#pragma unroll
    for (int r = 0; r < 4; ++r) {
        const size_t grow = (size_t)b * Nn + n0 + quad * 4 + r;
        paccm[grow * Dn + h * HDn + l15]      = acc[0][r];
        paccm[grow * Dn + h * HDn + 16 + l15] = acc[1][r];
        if (l15 == 0) plm[grow * Hn + h] = lsum[r];
    }
}

// ---------------------------------------------------------------------------
// Kernel 3: merge 2 partials + output projection. 8 rows/block, thread=col.
// ---------------------------------------------------------------------------
__global__ __launch_bounds__(256) void oproj_kernel(
    const float* __restrict__ pacc, const float* __restrict__ pl,
    const float* __restrict__ Wo, const float* __restrict__ bo,
    float* __restrict__ out)
{
    __shared__ float ysT[256][12];
    const int t = threadIdx.x;
    const int r0 = blockIdx.x * 8;
    const int h = t >> 5;
    const size_t PACC = (size_t)Bn * Nn * Dn;
    const size_t PL = (size_t)Bn * Nn * Hn;
#pragma unroll
    for (int i = 0; i < 8; ++i) {
        const size_t row = (size_t)(r0 + i);
        float l = 0.f, yv = 0.f;
#pragma unroll
        for (int m = 0; m < 2; ++m) {
            l  += pl[m * PL + row * Hn + h];
            yv += pacc[m * PACC + row * Dn + t];
        }
        ysT[t][i] = yv * __builtin_amdgcn_rcpf(l);
    }
    __syncthreads();

    float acc8[8];
#pragma unroll
    for (int i = 0; i < 8; ++i) acc8[i] = 0.f;
#pragma unroll 4
    for (int d = 0; d < 256; ++d) {
        const float wv = Wo[d * 256 + t];
        float yy[8];
        *(float4*)&yy[0] = *(const float4*)&ysT[d][0];
        *(float4*)&yy[4] = *(const float4*)&ysT[d][4];
#pragma unroll
        for (int i = 0; i < 8; ++i) acc8[i] = fmaf(yy[i], wv, acc8[i]);
    }
    const float bb = bo[t];
#pragma unroll
    for (int i = 0; i < 8; ++i)
        out[(size_t)(r0 + i) * 256 + t] = acc8[i] + bb;
}

// ---------------------------------------------------------------------------
extern "C" void kernel_launch(void* const* d_in, const int* in_sizes, int n_in,
                              void* d_out, int out_size, void* d_ws, size_t ws_size,
                              hipStream_t stream)
{
    const float* x    = (const float*)d_in[0];
    const float* topo = (const float*)d_in[1];
    const float* Wq   = (const float*)d_in[2];
    const float* bq   = (const float*)d_in[3];
    const float* Wk   = (const float*)d_in[4];
    const float* bk   = (const float*)d_in[5];
    const float* Wv   = (const float*)d_in[6];
    const float* bv   = (const float*)d_in[7];
    const float* Wo   = (const float*)d_in[8];
    const float* bo   = (const float*)d_in[9];
    float* out = (float*)d_out;

    char* ws = (char*)d_ws;
    const size_t MB = 1024 * 1024;
    h1* WT = (h1*)ws;
    h1* fq = (h1*)(ws + 1 * MB);
    h1* fk = (h1*)(ws + 9 * MB);
    h1* vT = (h1*)(ws + 17 * MB);
    float* pacc = (float*)(ws + 21 * MB);
    float* pl   = (float*)(ws + 37 * MB);

    cvtW_kernel<<<dim3(4, 4, 3), 256, 0, stream>>>(Wq, Wk, Wv, WT);
    proj_kernel<<<dim3(128, 6), 256, 0, stream>>>(x, WT, bq, bk, bv, fq, fk, vT);
    attn_kernel<<<dim3(Nn / NT, Bn, 2), 512, 0, stream>>>(fq, fk, vT, topo, pacc, pl);
    oproj_kernel<<<(Bn * Nn) / 8, 256, 0, stream>>>(pacc, pl, Wo, bo, out);
}

// Round 7
// 269.115 us; speedup vs baseline: 1.3130x; 1.3130x over previous
//
#include <hip/hip_runtime.h>
#include <math.h>

#define Bn 4
#define Nn 2048
#define Hn 8
#define HDn 32
#define Dn 256
#define MHALF 1024  // m-split: 2 partials merged in oproj
#define NT 64       // q-rows per attn block: 256 blocks = 1/CU, 2x K/V reuse

typedef _Float16 h1;
typedef __attribute__((ext_vector_type(8))) _Float16 h8;
typedef __attribute__((ext_vector_type(4))) float fx4;

#define QSCALE 0.35355339059327373f
// |S_raw| <= HD = 32, |S_raw*QSCALE*topo| <= 11.32 -> fixed softmax shift safe:
// p = e^{S-4} in [2.2e-7, 1503] -- fits f16, no running max needed.
#define SOFTMAX_SHIFT 4.0f

// ---------------------------------------------------------------------------
// Kernel 0: W -> f16 transpose via LDS tiles (coalesced both sides)
// ---------------------------------------------------------------------------
__global__ __launch_bounds__(256) void cvtW_kernel(
    const float* __restrict__ Wq, const float* __restrict__ Wk,
    const float* __restrict__ Wv, h1* __restrict__ WT)
{
    __shared__ float tw[64][65];
    const int w = blockIdx.z;
    const int d0 = blockIdx.y * 64, o0 = blockIdx.x * 64;
    const float* W = (w == 0) ? Wq : (w == 1) ? Wk : Wv;
    const int rr = threadIdx.x >> 6, cc = threadIdx.x & 63;
#pragma unroll
    for (int i = 0; i < 16; ++i)
        tw[rr + i * 4][cc] = W[(size_t)(d0 + rr + i * 4) * 256 + o0 + cc];
    __syncthreads();
#pragma unroll
    for (int i = 0; i < 16; ++i) {
        const int row = rr + i * 4;
        WT[(size_t)w * 65536 + (size_t)(o0 + row) * 256 + d0 + cc] = (h1)tw[cc][row];
    }
}

// ---------------------------------------------------------------------------
// Kernel 1: QKV projection via f16 MFMA (x split hi/lo for ~f32 accuracy).
// ---------------------------------------------------------------------------
__global__ __launch_bounds__(256) __attribute__((amdgpu_waves_per_eu(4, 4)))
void proj_kernel(
    const float* __restrict__ x, const h1* __restrict__ WT,
    const float* __restrict__ bq, const float* __restrict__ bk,
    const float* __restrict__ bv,
    h1* __restrict__ fq, h1* __restrict__ fk, h1* __restrict__ vT)
{
    __shared__ __align__(16) h1 fbuf[64][264];
    const int tid = threadIdx.x;
    const int w = tid >> 6;
    const int lane = tid & 63;
    const int quad = lane >> 4;
    const int l15 = lane & 15;
    const int wsel = blockIdx.y >> 1;
    const int hg = blockIdx.y & 1;
    const int r0 = blockIdx.x * 64;
    const int arow = r0 + w * 16 + l15;
    const int b = r0 >> 11, n0 = r0 & (Nn - 1);

    const h1* WTw = WT + (size_t)wsel * 65536;
    fx4 acc[8];
#pragma unroll
    for (int ct = 0; ct < 8; ++ct) acc[ct] = (fx4){0.f, 0.f, 0.f, 0.f};

    for (int ks = 0; ks < 8; ++ks) {
        float xv[8];
        *(float4*)&xv[0] = *(const float4*)&x[(size_t)arow * 256 + ks * 32 + quad * 8];
        *(float4*)&xv[4] = *(const float4*)&x[(size_t)arow * 256 + ks * 32 + quad * 8 + 4];
        h8 Ahi, Alo;
#pragma unroll
        for (int j = 0; j < 8; ++j) {
            const h1 hi = (h1)xv[j];
            Ahi[j] = hi;
            Alo[j] = (h1)(xv[j] - (float)hi);
        }
        h8 Bf[8];
#pragma unroll
        for (int ct = 0; ct < 8; ++ct)
            Bf[ct] = *(const h8*)&WTw[(size_t)(hg * 128 + ct * 16 + l15) * 256 + ks * 32 + quad * 8];
#pragma unroll
        for (int ct = 0; ct < 8; ++ct) {
            acc[ct] = __builtin_amdgcn_mfma_f32_16x16x32_f16(Ahi, Bf[ct], acc[ct], 0, 0, 0);
            acc[ct] = __builtin_amdgcn_mfma_f32_16x16x32_f16(Alo, Bf[ct], acc[ct], 0, 0, 0);
        }
    }

    const float* bias = (wsel == 0) ? bq : (wsel == 1) ? bk : bv;

    if (wsel < 2) {
        h1* f = (wsel == 0) ? fq : fk;
#pragma unroll
        for (int ct = 0; ct < 8; ++ct) {
            const int c = ct * 16 + l15;
            const float bb = bias[hg * 128 + c];
            const int hh4 = c >> 5, dd = c & 31;
#pragma unroll
            for (int r = 0; r < 4; ++r) {
                const float val = acc[ct][r] + bb;
                const float sv = __sinf(val), cv = __cosf(val);
                h1* fp = &fbuf[w * 16 + quad * 4 + r][hh4 * 64 + dd];
                fp[0]  = (h1)cv;
                fp[32] = (h1)sv;
            }
        }
        __syncthreads();
        const int row = tid >> 2, q4 = tid & 3;
#pragma unroll
        for (int g = 0; g < 8; ++g) {
            const int chunk = q4 + g * 4;
            const int hh4 = chunk >> 3, within = chunk & 7;
            const h8 val = *(const h8*)&fbuf[row][hh4 * 64 + within * 8];
            const int head = hg * 4 + hh4;
            *(h8*)&f[((size_t)(b * Hn + head) * Nn + n0 + row) * 64 + within * 8] = val;
        }
    } else {
        h1 (*vst)[132] = (h1(*)[132])fbuf;
#pragma unroll
        for (int ct = 0; ct < 8; ++ct) {
            const int c = ct * 16 + l15;
            const float bb = bias[hg * 128 + c];
#pragma unroll
            for (int r = 0; r < 4; ++r)
                vst[w * 16 + quad * 4 + r][c] = (h1)(acc[ct][r] + bb);
        }
        __syncthreads();
        const int c2 = tid & 127, half = tid >> 7;
        const int head = hg * 4 + (c2 >> 5), dd = c2 & 31;
        h1* vp = vT + ((size_t)((b * Hn + head) * HDn + dd)) * Nn + n0;
#pragma unroll
        for (int g = 0; g < 4; ++g) {
            const int gg = half * 4 + g;
            h8 pk;
#pragma unroll
            for (int j = 0; j < 8; ++j) pk[j] = vst[gg * 8 + j][c2];
            *(h8*)(vp + gg * 8) = pk;
        }
    }
}

// ---------------------------------------------------------------------------
// Kernel 2: fused attention. Block = 512 thr = 8 waves = ALL 8 heads of one
// (b, NT=64 q-rows, m-half). Grid 256 blocks = exactly 1 block/CU.
//
// LEDGER (r8-r13): falsified = {occupancy (r13: 56%, no gain), K/V load
// latency (r12: clean reg prefetch, no gain), barrier count (r10), bank
// conflicts (r10: 5.2M->1.0M, no change), scratch spills (r12)}.
// What fits ALL runs: wall time ~= L2 read bytes / ~7.5 TB/s.
//   r7/r10/r12 (NT=32, ~860MB L2): 111-127us.  r8/r13 (NT=16, ~1.7GB
//   because 2x blocks each re-read the full K/V m-half): 200-201us (2x).
// The kernel is L2-THROUGHPUT-BOUND on K/V fragment re-reads; occupancy,
// prefetch and barrier structure are all irrelevant at this wall.
//
// r14 CHANGE: NT 32 -> 64. Halves the number of n-blocks sharing each K/V
// byte's m-half -> L2 traffic ~860MB -> ~485MB (K 256 + V 128 + topo 67 +
// partials 34). launch_bounds(512,1): only 256 blocks exist, so 1 block/CU
// is the true residency; 256-VGPR budget holds the doubled per-thread state
// (qfr/acc/lsum/S x4 qs-tiles, ~160 regs) with NO spill. LDS 59.4KB < 64KB
// (tbuf padded [36] for aligned float4). Same proven iteration structure:
// topo 1-ahead register prefetch + lgkm-only raw barrier; fixed-shift
// softmax, no reductions in the loop.
// ---------------------------------------------------------------------------
__global__ __launch_bounds__(512, 1) void attn_kernel(
    const h1* __restrict__ fq, const h1* __restrict__ fk, const h1* __restrict__ vT,
    const float* __restrict__ topo, float* __restrict__ pacc, float* __restrict__ pl)
{
    __shared__ __align__(16) h1 Pw[8][NT][40];       // 41 KB per-wave P buffers
    __shared__ __align__(16) float tbuf[2][NT][36];  // 18.4 KB topo double buffer

    const int b = blockIdx.y;
    const int mh = blockIdx.z;
    const int n0 = blockIdx.x * NT;
    const int tid = threadIdx.x;
    const int w = tid >> 6;        // wave id = head
    const int h = w;
    const int lane = tid & 63;
    const int quad = lane >> 4;
    const int l15 = lane & 15;

    const h1* qfh = fq + (size_t)(b * Hn + h) * Nn * 64;
    const h1* kfh = fk + (size_t)(b * Hn + h) * Nn * 64;
    const h1* vTh = vT + (size_t)(b * Hn + h) * HDn * Nn;

    // topo cooperative-load mapping: thread -> (row, 4 cols); 64x32 f32 tile
    const int trow = tid >> 3, tcol4 = (tid & 7) * 4;
    const float* tpg = topo + (size_t)b * Nn * Nn + (size_t)(n0 + trow) * Nn + tcol4;

    h8 qfr[4][2];
#pragma unroll
    for (int qs = 0; qs < 4; ++qs)
#pragma unroll
        for (int ks = 0; ks < 2; ++ks)
            qfr[qs][ks] = *(const h8*)(qfh + (size_t)(n0 + qs * 16 + l15) * 64 + ks * 32 + quad * 8);

    fx4 acc[4][2];
    float lsum[4][4];
#pragma unroll
    for (int qs = 0; qs < 4; ++qs) {
#pragma unroll
        for (int ds = 0; ds < 2; ++ds) acc[qs][ds] = (fx4){0.f, 0.f, 0.f, 0.f};
#pragma unroll
        for (int r = 0; r < 4; ++r) lsum[qs][r] = 0.f;
    }

    const int mbase = mh * MHALF;
    const fx4 z4 = {0.f, 0.f, 0.f, 0.f};

    float4 rt = *(const float4*)(tpg + mbase);   // prefetch topo tile 0

    for (int it = 0; it < MHALF / 32; ++it) {
        const int m0 = mbase + it * 32;
        const int cur = it & 1;

        // commit prefetched topo tile to LDS, issue next tile's load
        *(float4*)&tbuf[cur][trow][tcol4] = rt;
        if (it < MHALF / 32 - 1) rt = *(const float4*)(tpg + m0 + 32);
        // raw barrier: waits own LDS writes only; global prefetch stays in flight
        __asm__ volatile("s_waitcnt lgkmcnt(0)\n\ts_barrier" ::: "memory");

        // K fragments + V fragments (per-head, L2-served)
        h8 kfr[2][2];
#pragma unroll
        for (int ms = 0; ms < 2; ++ms)
#pragma unroll
            for (int ks = 0; ks < 2; ++ks)
                kfr[ms][ks] = *(const h8*)(kfh + (size_t)(m0 + ms * 16 + l15) * 64 + ks * 32 + quad * 8);
        h8 bV[2];
#pragma unroll
        for (int ds = 0; ds < 2; ++ds)
            bV[ds] = *(const h8*)(vTh + (size_t)(ds * 16 + l15) * Nn + m0 + quad * 8);

        // S = Qf @ Kf^T  (4 q-subtiles x 2 m-subtiles)
        fx4 S[4][2];
#pragma unroll
        for (int qs = 0; qs < 4; ++qs)
#pragma unroll
            for (int ms = 0; ms < 2; ++ms) {
                fx4 tmp = __builtin_amdgcn_mfma_f32_16x16x32_f16(qfr[qs][0], kfr[ms][0], z4, 0, 0, 0);
                S[qs][ms] = __builtin_amdgcn_mfma_f32_16x16x32_f16(qfr[qs][1], kfr[ms][1], tmp, 0, 0, 0);
            }

        // p = e^{S*topo*QSCALE - 4}; topo from LDS
#pragma unroll
        for (int qs = 0; qs < 4; ++qs)
#pragma unroll
            for (int ms = 0; ms < 2; ++ms)
#pragma unroll
                for (int r = 0; r < 4; ++r) {
                    const float tv = tbuf[cur][qs * 16 + quad * 4 + r][ms * 16 + l15];
                    const float p = __expf(fmaf(S[qs][ms][r] * tv, QSCALE, -SOFTMAX_SHIFT));
                    lsum[qs][r] += p;
                    Pw[w][qs * 16 + quad * 4 + r][ms * 16 + l15] = (h1)p;
                }
        __asm__ volatile("s_waitcnt lgkmcnt(0)" ::: "memory");

        // PV
        h8 aP[4];
#pragma unroll
        for (int qs = 0; qs < 4; ++qs)
            aP[qs] = *(const h8*)&Pw[w][qs * 16 + l15][quad * 8];
#pragma unroll
        for (int qs = 0; qs < 4; ++qs)
#pragma unroll
            for (int ds = 0; ds < 2; ++ds)
                acc[qs][ds] = __builtin_amdgcn_mfma_f32_16x16x32_f16(aP[qs], bV[ds], acc[qs][ds], 0, 0, 0);
    }

    // epilogue: reduce l across the 16 col-lanes, write partials
#pragma unroll
    for (int qs = 0; qs < 4; ++qs)
#pragma unroll
        for (int r = 0; r < 4; ++r)
#pragma unroll
            for (int off = 1; off <= 8; off <<= 1)
                lsum[qs][r] += __shfl_xor(lsum[qs][r], off);

    float* paccm = pacc + (size_t)mh * Bn * Nn * Dn;
    float* plm   = pl   + (size_t)mh * Bn * Nn * Hn;
#pragma unroll
    for (int qs = 0; qs < 4; ++qs)
#pragma unroll
        for (int r = 0; r < 4; ++r) {
            const size_t grow = (size_t)b * Nn + n0 + qs * 16 + quad * 4 + r;
            paccm[grow * Dn + h * HDn + l15]      = acc[qs][0][r];
            paccm[grow * Dn + h * HDn + 16 + l15] = acc[qs][1][r];
            if (l15 == 0) plm[grow * Hn + h] = lsum[qs][r];
        }
}

// ---------------------------------------------------------------------------
// Kernel 3: merge 2 partials + output projection. 8 rows/block, thread=col.
// ---------------------------------------------------------------------------
__global__ __launch_bounds__(256) void oproj_kernel(
    const float* __restrict__ pacc, const float* __restrict__ pl,
    const float* __restrict__ Wo, const float* __restrict__ bo,
    float* __restrict__ out)
{
    __shared__ float ysT[256][12];
    const int t = threadIdx.x;
    const int r0 = blockIdx.x * 8;
    const int h = t >> 5;
    const size_t PACC = (size_t)Bn * Nn * Dn;
    const size_t PL = (size_t)Bn * Nn * Hn;
#pragma unroll
    for (int i = 0; i < 8; ++i) {
        const size_t row = (size_t)(r0 + i);
        float l = 0.f, yv = 0.f;
#pragma unroll
        for (int m = 0; m < 2; ++m) {
            l  += pl[m * PL + row * Hn + h];
            yv += pacc[m * PACC + row * Dn + t];
        }
        ysT[t][i] = yv * __builtin_amdgcn_rcpf(l);
    }
    __syncthreads();

    float acc8[8];
#pragma unroll
    for (int i = 0; i < 8; ++i) acc8[i] = 0.f;
#pragma unroll 4
    for (int d = 0; d < 256; ++d) {
        const float wv = Wo[d * 256 + t];
        float yy[8];
        *(float4*)&yy[0] = *(const float4*)&ysT[d][0];
        *(float4*)&yy[4] = *(const float4*)&ysT[d][4];
#pragma unroll
        for (int i = 0; i < 8; ++i) acc8[i] = fmaf(yy[i], wv, acc8[i]);
    }
    const float bb = bo[t];
#pragma unroll
    for (int i = 0; i < 8; ++i)
        out[(size_t)(r0 + i) * 256 + t] = acc8[i] + bb;
}

// ---------------------------------------------------------------------------
extern "C" void kernel_launch(void* const* d_in, const int* in_sizes, int n_in,
                              void* d_out, int out_size, void* d_ws, size_t ws_size,
                              hipStream_t stream)
{
    const float* x    = (const float*)d_in[0];
    const float* topo = (const float*)d_in[1];
    const float* Wq   = (const float*)d_in[2];
    const float* bq   = (const float*)d_in[3];
    const float* Wk   = (const float*)d_in[4];
    const float* bk   = (const float*)d_in[5];
    const float* Wv   = (const float*)d_in[6];
    const float* bv   = (const float*)d_in[7];
    const float* Wo   = (const float*)d_in[8];
    const float* bo   = (const float*)d_in[9];
    float* out = (float*)d_out;

    char* ws = (char*)d_ws;
    const size_t MB = 1024 * 1024;
    h1* WT = (h1*)ws;
    h1* fq = (h1*)(ws + 1 * MB);
    h1* fk = (h1*)(ws + 9 * MB);
    h1* vT = (h1*)(ws + 17 * MB);
    float* pacc = (float*)(ws + 21 * MB);
    float* pl   = (float*)(ws + 37 * MB);

    cvtW_kernel<<<dim3(4, 4, 3), 256, 0, stream>>>(Wq, Wk, Wv, WT);
    proj_kernel<<<dim3(128, 6), 256, 0, stream>>>(x, WT, bq, bk, bv, fq, fk, vT);
    attn_kernel<<<dim3(Nn / NT, Bn, 2), 512, 0, stream>>>(fq, fk, vT, topo, pacc, pl);
    oproj_kernel<<<(Bn * Nn) / 8, 256, 0, stream>>>(pacc, pl, Wo, bo, out);
}

// Round 9
// 232.385 us; speedup vs baseline: 1.5205x; 1.1581x over previous
//
#include <hip/hip_runtime.h>
#include <math.h>

#define Bn 4
#define Nn 2048
#define Hn 8
#define HDn 32
#define Dn 256
#define MHALF 1024  // m-split: 2 partials merged in oproj
#define NT 64       // q-rows per attn block: 256 blocks = 1/CU, min L2 traffic

typedef _Float16 h1;
typedef __attribute__((ext_vector_type(2))) _Float16 h2;
typedef __attribute__((ext_vector_type(2))) __fp16 g2;   // cvt_pkrtz return type
typedef __attribute__((ext_vector_type(8))) _Float16 h8;
typedef __attribute__((ext_vector_type(4))) float fx4;

#define QSCALE 0.35355339059327373f
// exp folded to exp2: p = 2^{(S*topo)*QSCALE*log2e - 4*log2e}
#define QS_L2E 0.5101185553493001f   // QSCALE * log2(e)
#define SH_L2E 5.770780163555851f    // 4 * log2(e)

// ---------------------------------------------------------------------------
// Kernel 0: W -> f16 transpose via LDS tiles (coalesced both sides)
// ---------------------------------------------------------------------------
__global__ __launch_bounds__(256) void cvtW_kernel(
    const float* __restrict__ Wq, const float* __restrict__ Wk,
    const float* __restrict__ Wv, h1* __restrict__ WT)
{
    __shared__ float tw[64][65];
    const int w = blockIdx.z;
    const int d0 = blockIdx.y * 64, o0 = blockIdx.x * 64;
    const float* W = (w == 0) ? Wq : (w == 1) ? Wk : Wv;
    const int rr = threadIdx.x >> 6, cc = threadIdx.x & 63;
#pragma unroll
    for (int i = 0; i < 16; ++i)
        tw[rr + i * 4][cc] = W[(size_t)(d0 + rr + i * 4) * 256 + o0 + cc];
    __syncthreads();
#pragma unroll
    for (int i = 0; i < 16; ++i) {
        const int row = rr + i * 4;
        WT[(size_t)w * 65536 + (size_t)(o0 + row) * 256 + d0 + cc] = (h1)tw[cc][row];
    }
}

// ---------------------------------------------------------------------------
// Kernel 1: QKV projection via f16 MFMA (x split hi/lo for ~f32 accuracy).
// vT is written with a sigma-permuted column order within each 32-m block:
//   sigma(z) = ((z&7)>>2)*16 + (z>>3)*4 + (z&3)   (bijective bit shuffle)
// so that attn's swapped-QK^T P fragments feed PV directly from registers
// (P[q][m] for lane (quad,l15): m = ms*16 + quad*4 + r  ==  sigma(quad*8+j)).
// ---------------------------------------------------------------------------
__global__ __launch_bounds__(256) __attribute__((amdgpu_waves_per_eu(4, 4)))
void proj_kernel(
    const float* __restrict__ x, const h1* __restrict__ WT,
    const float* __restrict__ bq, const float* __restrict__ bk,
    const float* __restrict__ bv,
    h1* __restrict__ fq, h1* __restrict__ fk, h1* __restrict__ vT)
{
    __shared__ __align__(16) h1 fbuf[64][264];
    const int tid = threadIdx.x;
    const int w = tid >> 6;
    const int lane = tid & 63;
    const int quad = lane >> 4;
    const int l15 = lane & 15;
    const int wsel = blockIdx.y >> 1;
    const int hg = blockIdx.y & 1;
    const int r0 = blockIdx.x * 64;
    const int arow = r0 + w * 16 + l15;
    const int b = r0 >> 11, n0 = r0 & (Nn - 1);

    const h1* WTw = WT + (size_t)wsel * 65536;
    fx4 acc[8];
#pragma unroll
    for (int ct = 0; ct < 8; ++ct) acc[ct] = (fx4){0.f, 0.f, 0.f, 0.f};

    for (int ks = 0; ks < 8; ++ks) {
        float xv[8];
        *(float4*)&xv[0] = *(const float4*)&x[(size_t)arow * 256 + ks * 32 + quad * 8];
        *(float4*)&xv[4] = *(const float4*)&x[(size_t)arow * 256 + ks * 32 + quad * 8 + 4];
        h8 Ahi, Alo;
#pragma unroll
        for (int j = 0; j < 8; ++j) {
            const h1 hi = (h1)xv[j];
            Ahi[j] = hi;
            Alo[j] = (h1)(xv[j] - (float)hi);
        }
        h8 Bf[8];
#pragma unroll
        for (int ct = 0; ct < 8; ++ct)
            Bf[ct] = *(const h8*)&WTw[(size_t)(hg * 128 + ct * 16 + l15) * 256 + ks * 32 + quad * 8];
#pragma unroll
        for (int ct = 0; ct < 8; ++ct) {
            acc[ct] = __builtin_amdgcn_mfma_f32_16x16x32_f16(Ahi, Bf[ct], acc[ct], 0, 0, 0);
            acc[ct] = __builtin_amdgcn_mfma_f32_16x16x32_f16(Alo, Bf[ct], acc[ct], 0, 0, 0);
        }
    }

    const float* bias = (wsel == 0) ? bq : (wsel == 1) ? bk : bv;

    if (wsel < 2) {
        h1* f = (wsel == 0) ? fq : fk;
#pragma unroll
        for (int ct = 0; ct < 8; ++ct) {
            const int c = ct * 16 + l15;
            const float bb = bias[hg * 128 + c];
            const int hh4 = c >> 5, dd = c & 31;
#pragma unroll
            for (int r = 0; r < 4; ++r) {
                const float val = acc[ct][r] + bb;
                const float sv = __sinf(val), cv = __cosf(val);
                h1* fp = &fbuf[w * 16 + quad * 4 + r][hh4 * 64 + dd];
                fp[0]  = (h1)cv;
                fp[32] = (h1)sv;
            }
        }
        __syncthreads();
        const int row = tid >> 2, q4 = tid & 3;
#pragma unroll
        for (int g = 0; g < 8; ++g) {
            const int chunk = q4 + g * 4;
            const int hh4 = chunk >> 3, within = chunk & 7;
            const h8 val = *(const h8*)&fbuf[row][hh4 * 64 + within * 8];
            const int head = hg * 4 + hh4;
            *(h8*)&f[((size_t)(b * Hn + head) * Nn + n0 + row) * 64 + within * 8] = val;
        }
    } else {
        h1 (*vst)[132] = (h1(*)[132])fbuf;
#pragma unroll
        for (int ct = 0; ct < 8; ++ct) {
            const int c = ct * 16 + l15;
            const float bb = bias[hg * 128 + c];
#pragma unroll
            for (int r = 0; r < 4; ++r)
                vst[w * 16 + quad * 4 + r][c] = (h1)(acc[ct][r] + bb);
        }
        __syncthreads();
        const int c2 = tid & 127, half = tid >> 7;
        const int head = hg * 4 + (c2 >> 5), dd = c2 & 31;
        h1* vp = vT + ((size_t)((b * Hn + head) * HDn + dd)) * Nn + n0;
#pragma unroll
        for (int g = 0; g < 4; ++g) {
            const int gg = half * 4 + g;
            h8 pk;
#pragma unroll
            for (int j = 0; j < 8; ++j) {
                const int zz = gg * 8 + j;          // output col offset 0..63
                const int blk = zz >> 5, z = zz & 31;
                const int src = blk * 32 + ((z & 7) >> 2) * 16 + (z >> 3) * 4 + (z & 3);
                pk[j] = vst[src][c2];               // sigma-permuted gather
            }
            *(h8*)(vp + gg * 8) = pk;
        }
    }
}

// ---------------------------------------------------------------------------
// Kernel 2: fused attention -- swapped-QK^T, fully in-register softmax.
//
// LEDGER: falsified = {occupancy(r13), K/V latency(r12), barrier count(r10),
// bank conflicts(r10), scratch(r12), L2 bytes alone(r14: halved, no change)}.
// Model fitting ALL runs: dur ~= max(L2_bytes/7.5TB/s, ~112us compute term).
// The compute term = per-S-element softmax cost (~25-30 issue cyc each:
// b32 topo read + ~10 VALU + cvt + b16 P write + P LDS round-trip on the
// serial chain), 134M elements, ~34% overlapped at 2 waves/SIMD.
//
// r15/r16 CHANGE: S2 = mfma(K,Q) instead of mfma(Q,K). Output lane mapping
// becomes q=l15 (fixed per lane), m=ms*16+quad*4+r:
//  - topo reads become b128 (r is contiguous): 32 b32 -> 8 b128 per iter.
//  - P stays in registers: cvt_pkrtz packs (r,r+1) pairs; with vT stored
//    sigma-permuted (see proj), {pk[0][0],pk[0][1],pk[1][0],pk[1][1]} IS the
//    PV A-fragment. No Pw LDS buffer, no mid-iter lgkmcnt, no LDS round trip.
//  - lsum is per-lane scalar per qs; single cross-quad shfl reduce at end.
// LDS 59.4KB -> 20.5KB. exp folded to exp2f (native v_exp_f32, no log2e mul).
// K/V loads issued before the lgkm-only barrier so they fly across it.
// (r16: fixed cvt_pkrtz return-type mismatch via __builtin_bit_cast.)
// ---------------------------------------------------------------------------
__global__ __launch_bounds__(512, 1) void attn_kernel(
    const h1* __restrict__ fq, const h1* __restrict__ fk, const h1* __restrict__ vT,
    const float* __restrict__ topo, float* __restrict__ pacc, float* __restrict__ pl)
{
    __shared__ __align__(16) float tbuf[2][NT][40];  // 20.5 KB topo double buffer

    const int b = blockIdx.y;
    const int mh = blockIdx.z;
    const int n0 = blockIdx.x * NT;
    const int tid = threadIdx.x;
    const int w = tid >> 6;        // wave id = head
    const int h = w;
    const int lane = tid & 63;
    const int quad = lane >> 4;
    const int l15 = lane & 15;

    const h1* qfh = fq + (size_t)(b * Hn + h) * Nn * 64;
    const h1* kfh = fk + (size_t)(b * Hn + h) * Nn * 64;
    const h1* vTh = vT + (size_t)(b * Hn + h) * HDn * Nn;

    // topo cooperative-load mapping: thread -> (row, 4 cols); 64x32 f32 tile
    const int trow = tid >> 3, tcol4 = (tid & 7) * 4;
    const float* tpg = topo + (size_t)b * Nn * Nn + (size_t)(n0 + trow) * Nn + tcol4;

    h8 qfr[4][2];
#pragma unroll
    for (int qs = 0; qs < 4; ++qs)
#pragma unroll
        for (int ks = 0; ks < 2; ++ks)
            qfr[qs][ks] = *(const h8*)(qfh + (size_t)(n0 + qs * 16 + l15) * 64 + ks * 32 + quad * 8);

    fx4 acc[4][2];
    float lsum[4];
#pragma unroll
    for (int qs = 0; qs < 4; ++qs) {
#pragma unroll
        for (int ds = 0; ds < 2; ++ds) acc[qs][ds] = (fx4){0.f, 0.f, 0.f, 0.f};
        lsum[qs] = 0.f;
    }

    const int mbase = mh * MHALF;
    const fx4 z4 = {0.f, 0.f, 0.f, 0.f};

    float4 rt = *(const float4*)(tpg + mbase);   // prefetch topo tile 0

    for (int it = 0; it < MHALF / 32; ++it) {
        const int m0 = mbase + it * 32;
        const int cur = it & 1;

        // K/V fragments: issue BEFORE the barrier (global loads ride across
        // the lgkm-only barrier; no LDS dependency)
        h8 kfr[2][2];
#pragma unroll
        for (int ms = 0; ms < 2; ++ms)
#pragma unroll
            for (int ks = 0; ks < 2; ++ks)
                kfr[ms][ks] = *(const h8*)(kfh + (size_t)(m0 + ms * 16 + l15) * 64 + ks * 32 + quad * 8);
        h8 bV[2];
#pragma unroll
        for (int ds = 0; ds < 2; ++ds)
            bV[ds] = *(const h8*)(vTh + (size_t)(ds * 16 + l15) * Nn + m0 + quad * 8);

        // commit prefetched topo tile to LDS, issue next tile's load
        *(float4*)&tbuf[cur][trow][tcol4] = rt;
        if (it < MHALF / 32 - 1) rt = *(const float4*)(tpg + m0 + 32);
        // raw barrier: waits own LDS writes only; global loads stay in flight
        __asm__ volatile("s_waitcnt lgkmcnt(0)\n\ts_barrier" ::: "memory");

#pragma unroll
        for (int qs = 0; qs < 4; ++qs) {
            h2 pk[2][2];
#pragma unroll
            for (int ms = 0; ms < 2; ++ms) {
                // swapped: S2[row=m(quad*4+r)][col=q(l15)] = K @ Q^T
                fx4 tmp = __builtin_amdgcn_mfma_f32_16x16x32_f16(kfr[ms][0], qfr[qs][0], z4, 0, 0, 0);
                fx4 S2  = __builtin_amdgcn_mfma_f32_16x16x32_f16(kfr[ms][1], qfr[qs][1], tmp, 0, 0, 0);
                const fx4 tv = *(const fx4*)&tbuf[cur][qs * 16 + l15][ms * 16 + quad * 4];
                const float p0 = exp2f(fmaf(S2[0] * tv[0], QS_L2E, -SH_L2E));
                const float p1 = exp2f(fmaf(S2[1] * tv[1], QS_L2E, -SH_L2E));
                const float p2 = exp2f(fmaf(S2[2] * tv[2], QS_L2E, -SH_L2E));
                const float p3 = exp2f(fmaf(S2[3] * tv[3], QS_L2E, -SH_L2E));
                lsum[qs] += (p0 + p1) + (p2 + p3);
                pk[ms][0] = __builtin_bit_cast(h2, __builtin_amdgcn_cvt_pkrtz(p0, p1));
                pk[ms][1] = __builtin_bit_cast(h2, __builtin_amdgcn_cvt_pkrtz(p2, p3));
            }
            // PA fragment: lane's own 8 p-values in sigma-matched k-order
            union { h8 v; h2 p[4]; } pa;
            pa.p[0] = pk[0][0]; pa.p[1] = pk[0][1];
            pa.p[2] = pk[1][0]; pa.p[3] = pk[1][1];
#pragma unroll
            for (int ds = 0; ds < 2; ++ds)
                acc[qs][ds] = __builtin_amdgcn_mfma_f32_16x16x32_f16(pa.v, bV[ds], acc[qs][ds], 0, 0, 0);
        }
    }

    // epilogue: lsum lives at q=l15 per qs; reduce across the 4 quads
#pragma unroll
    for (int qs = 0; qs < 4; ++qs) {
        lsum[qs] += __shfl_xor(lsum[qs], 16);
        lsum[qs] += __shfl_xor(lsum[qs], 32);
    }

    float* paccm = pacc + (size_t)mh * Bn * Nn * Dn;
    float* plm   = pl   + (size_t)mh * Bn * Nn * Hn;
#pragma unroll
    for (int qs = 0; qs < 4; ++qs) {
#pragma unroll
        for (int r = 0; r < 4; ++r) {
            const size_t grow = (size_t)b * Nn + n0 + qs * 16 + quad * 4 + r;
            paccm[grow * Dn + h * HDn + l15]      = acc[qs][0][r];
            paccm[grow * Dn + h * HDn + 16 + l15] = acc[qs][1][r];
        }
        if (quad == 0)
            plm[((size_t)b * Nn + n0 + qs * 16 + l15) * Hn + h] = lsum[qs];
    }
}

// ---------------------------------------------------------------------------
// Kernel 3: merge 2 partials + output projection. 8 rows/block, thread=col.
// ---------------------------------------------------------------------------
__global__ __launch_bounds__(256) void oproj_kernel(
    const float* __restrict__ pacc, const float* __restrict__ pl,
    const float* __restrict__ Wo, const float* __restrict__ bo,
    float* __restrict__ out)
{
    __shared__ float ysT[256][12];
    const int t = threadIdx.x;
    const int r0 = blockIdx.x * 8;
    const int h = t >> 5;
    const size_t PACC = (size_t)Bn * Nn * Dn;
    const size_t PL = (size_t)Bn * Nn * Hn;
#pragma unroll
    for (int i = 0; i < 8; ++i) {
        const size_t row = (size_t)(r0 + i);
        float l = 0.f, yv = 0.f;
#pragma unroll
        for (int m = 0; m < 2; ++m) {
            l  += pl[m * PL + row * Hn + h];
            yv += pacc[m * PACC + row * Dn + t];
        }
        ysT[t][i] = yv * __builtin_amdgcn_rcpf(l);
    }
    __syncthreads();

    float acc8[8];
#pragma unroll
    for (int i = 0; i < 8; ++i) acc8[i] = 0.f;
#pragma unroll 4
    for (int d = 0; d < 256; ++d) {
        const float wv = Wo[d * 256 + t];
        float yy[8];
        *(float4*)&yy[0] = *(const float4*)&ysT[d][0];
        *(float4*)&yy[4] = *(const float4*)&ysT[d][4];
#pragma unroll
        for (int i = 0; i < 8; ++i) acc8[i] = fmaf(yy[i], wv, acc8[i]);
    }
    const float bb = bo[t];
#pragma unroll
    for (int i = 0; i < 8; ++i)
        out[(size_t)(r0 + i) * 256 + t] = acc8[i] + bb;
}

// ---------------------------------------------------------------------------
extern "C" void kernel_launch(void* const* d_in, const int* in_sizes, int n_in,
                              void* d_out, int out_size, void* d_ws, size_t ws_size,
                              hipStream_t stream)
{
    const float* x    = (const float*)d_in[0];
    const float* topo = (const float*)d_in[1];
    const float* Wq   = (const float*)d_in[2];
    const float* bq   = (const float*)d_in[3];
    const float* Wk   = (const float*)d_in[4];
    const float* bk   = (const float*)d_in[5];
    const float* Wv   = (const float*)d_in[6];
    const float* bv   = (const float*)d_in[7];
    const float* Wo   = (const float*)d_in[8];
    const float* bo   = (const float*)d_in[9];
    float* out = (float*)d_out;

    char* ws = (char*)d_ws;
    const size_t MB = 1024 * 1024;
    h1* WT = (h1*)ws;
    h1* fq = (h1*)(ws + 1 * MB);
    h1* fk = (h1*)(ws + 9 * MB);
    h1* vT = (h1*)(ws + 17 * MB);
    float* pacc = (float*)(ws + 21 * MB);
    float* pl   = (float*)(ws + 37 * MB);

    cvtW_kernel<<<dim3(4, 4, 3), 256, 0, stream>>>(Wq, Wk, Wv, WT);
    proj_kernel<<<dim3(128, 6), 256, 0, stream>>>(x, WT, bq, bk, bv, fq, fk, vT);
    attn_kernel<<<dim3(Nn / NT, Bn, 2), 512, 0, stream>>>(fq, fk, vT, topo, pacc, pl);
    oproj_kernel<<<(Bn * Nn) / 8, 256, 0, stream>>>(pacc, pl, Wo, bo, out);
}

// Round 10
// 212.901 us; speedup vs baseline: 1.6596x; 1.0915x over previous
//
#include <hip/hip_runtime.h>
#include <math.h>

#define Bn 4
#define Nn 2048
#define Hn 8
#define HDn 32
#define Dn 256
#define MHALF 1024  // m-split: 2 partials merged in oproj
#define NT 64       // q-rows per attn block: 256 blocks = 1/CU, min L2 traffic

typedef _Float16 h1;
typedef __attribute__((ext_vector_type(2))) _Float16 h2;
typedef __attribute__((ext_vector_type(8))) _Float16 h8;
typedef __attribute__((ext_vector_type(4))) float fx4;

#define QSCALE 0.35355339059327373f
// exp folded to exp2: p = 2^{(S*topo)*QSCALE*log2e - 4*log2e}
#define QS_L2E 0.5101185553493001f   // QSCALE * log2(e)
#define SH_L2E 5.770780163555851f    // 4 * log2(e)

// ---------------------------------------------------------------------------
// Kernel 0: W -> f16 transpose via LDS tiles (coalesced both sides).
// r17: also emits Wo^T (blockIdx.z==3) for the MFMA-based oproj.
// ---------------------------------------------------------------------------
__global__ __launch_bounds__(256) void cvtW_kernel(
    const float* __restrict__ Wq, const float* __restrict__ Wk,
    const float* __restrict__ Wv, const float* __restrict__ Wo,
    h1* __restrict__ WT)
{
    __shared__ float tw[64][65];
    const int w = blockIdx.z;
    const int d0 = blockIdx.y * 64, o0 = blockIdx.x * 64;
    const float* W = (w == 0) ? Wq : (w == 1) ? Wk : (w == 2) ? Wv : Wo;
    const int rr = threadIdx.x >> 6, cc = threadIdx.x & 63;
#pragma unroll
    for (int i = 0; i < 16; ++i)
        tw[rr + i * 4][cc] = W[(size_t)(d0 + rr + i * 4) * 256 + o0 + cc];
    __syncthreads();
#pragma unroll
    for (int i = 0; i < 16; ++i) {
        const int row = rr + i * 4;
        WT[(size_t)w * 65536 + (size_t)(o0 + row) * 256 + d0 + cc] = (h1)tw[cc][row];
    }
}

// ---------------------------------------------------------------------------
// Kernel 1: QKV projection via f16 MFMA (x split hi/lo for ~f32 accuracy).
// vT is written with a sigma-permuted column order within each 32-m block:
//   sigma(z) = ((z&7)>>2)*16 + (z>>3)*4 + (z&3)   (bijective bit shuffle)
// so that attn's swapped-QK^T P fragments feed PV directly from registers
// (P[q][m] for lane (quad,l15): m = ms*16 + quad*4 + r  ==  sigma(quad*8+j)).
// ---------------------------------------------------------------------------
__global__ __launch_bounds__(256) __attribute__((amdgpu_waves_per_eu(4, 4)))
void proj_kernel(
    const float* __restrict__ x, const h1* __restrict__ WT,
    const float* __restrict__ bq, const float* __restrict__ bk,
    const float* __restrict__ bv,
    h1* __restrict__ fq, h1* __restrict__ fk, h1* __restrict__ vT)
{
    __shared__ __align__(16) h1 fbuf[64][264];
    const int tid = threadIdx.x;
    const int w = tid >> 6;
    const int lane = tid & 63;
    const int quad = lane >> 4;
    const int l15 = lane & 15;
    const int wsel = blockIdx.y >> 1;
    const int hg = blockIdx.y & 1;
    const int r0 = blockIdx.x * 64;
    const int arow = r0 + w * 16 + l15;
    const int b = r0 >> 11, n0 = r0 & (Nn - 1);

    const h1* WTw = WT + (size_t)wsel * 65536;
    fx4 acc[8];
#pragma unroll
    for (int ct = 0; ct < 8; ++ct) acc[ct] = (fx4){0.f, 0.f, 0.f, 0.f};

    for (int ks = 0; ks < 8; ++ks) {
        float xv[8];
        *(float4*)&xv[0] = *(const float4*)&x[(size_t)arow * 256 + ks * 32 + quad * 8];
        *(float4*)&xv[4] = *(const float4*)&x[(size_t)arow * 256 + ks * 32 + quad * 8 + 4];
        h8 Ahi, Alo;
#pragma unroll
        for (int j = 0; j < 8; ++j) {
            const h1 hi = (h1)xv[j];
            Ahi[j] = hi;
            Alo[j] = (h1)(xv[j] - (float)hi);
        }
        h8 Bf[8];
#pragma unroll
        for (int ct = 0; ct < 8; ++ct)
            Bf[ct] = *(const h8*)&WTw[(size_t)(hg * 128 + ct * 16 + l15) * 256 + ks * 32 + quad * 8];
#pragma unroll
        for (int ct = 0; ct < 8; ++ct) {
            acc[ct] = __builtin_amdgcn_mfma_f32_16x16x32_f16(Ahi, Bf[ct], acc[ct], 0, 0, 0);
            acc[ct] = __builtin_amdgcn_mfma_f32_16x16x32_f16(Alo, Bf[ct], acc[ct], 0, 0, 0);
        }
    }

    const float* bias = (wsel == 0) ? bq : (wsel == 1) ? bk : bv;

    if (wsel < 2) {
        h1* f = (wsel == 0) ? fq : fk;
#pragma unroll
        for (int ct = 0; ct < 8; ++ct) {
            const int c = ct * 16 + l15;
            const float bb = bias[hg * 128 + c];
            const int hh4 = c >> 5, dd = c & 31;
#pragma unroll
            for (int r = 0; r < 4; ++r) {
                const float val = acc[ct][r] + bb;
                const float sv = __sinf(val), cv = __cosf(val);
                h1* fp = &fbuf[w * 16 + quad * 4 + r][hh4 * 64 + dd];
                fp[0]  = (h1)cv;
                fp[32] = (h1)sv;
            }
        }
        __syncthreads();
        const int row = tid >> 2, q4 = tid & 3;
#pragma unroll
        for (int g = 0; g < 8; ++g) {
            const int chunk = q4 + g * 4;
            const int hh4 = chunk >> 3, within = chunk & 7;
            const h8 val = *(const h8*)&fbuf[row][hh4 * 64 + within * 8];
            const int head = hg * 4 + hh4;
            *(h8*)&f[((size_t)(b * Hn + head) * Nn + n0 + row) * 64 + within * 8] = val;
        }
    } else {
        h1 (*vst)[132] = (h1(*)[132])fbuf;
#pragma unroll
        for (int ct = 0; ct < 8; ++ct) {
            const int c = ct * 16 + l15;
            const float bb = bias[hg * 128 + c];
#pragma unroll
            for (int r = 0; r < 4; ++r)
                vst[w * 16 + quad * 4 + r][c] = (h1)(acc[ct][r] + bb);
        }
        __syncthreads();
        const int c2 = tid & 127, half = tid >> 7;
        const int head = hg * 4 + (c2 >> 5), dd = c2 & 31;
        h1* vp = vT + ((size_t)((b * Hn + head) * HDn + dd)) * Nn + n0;
#pragma unroll
        for (int g = 0; g < 4; ++g) {
            const int gg = half * 4 + g;
            h8 pk;
#pragma unroll
            for (int j = 0; j < 8; ++j) {
                const int zz = gg * 8 + j;          // output col offset 0..63
                const int blk = zz >> 5, z = zz & 31;
                const int src = blk * 32 + ((z & 7) >> 2) * 16 + (z >> 3) * 4 + (z & 3);
                pk[j] = vst[src][c2];               // sigma-permuted gather
            }
            *(h8*)(vp + gg * 8) = pk;
        }
    }
}

// ---------------------------------------------------------------------------
// Kernel 2: fused attention -- swapped-QK^T, fully in-register softmax.
// (r16, VERIFIED: 75us, VALU 53%, Mfma 14%, bank conflicts 0. UNTOUCHED.)
// ---------------------------------------------------------------------------
__global__ __launch_bounds__(512, 1) void attn_kernel(
    const h1* __restrict__ fq, const h1* __restrict__ fk, const h1* __restrict__ vT,
    const float* __restrict__ topo, float* __restrict__ pacc, float* __restrict__ pl)
{
    __shared__ __align__(16) float tbuf[2][NT][40];  // 20.5 KB topo double buffer

    const int b = blockIdx.y;
    const int mh = blockIdx.z;
    const int n0 = blockIdx.x * NT;
    const int tid = threadIdx.x;
    const int w = tid >> 6;        // wave id = head
    const int h = w;
    const int lane = tid & 63;
    const int quad = lane >> 4;
    const int l15 = lane & 15;

    const h1* qfh = fq + (size_t)(b * Hn + h) * Nn * 64;
    const h1* kfh = fk + (size_t)(b * Hn + h) * Nn * 64;
    const h1* vTh = vT + (size_t)(b * Hn + h) * HDn * Nn;

    // topo cooperative-load mapping: thread -> (row, 4 cols); 64x32 f32 tile
    const int trow = tid >> 3, tcol4 = (tid & 7) * 4;
    const float* tpg = topo + (size_t)b * Nn * Nn + (size_t)(n0 + trow) * Nn + tcol4;

    h8 qfr[4][2];
#pragma unroll
    for (int qs = 0; qs < 4; ++qs)
#pragma unroll
        for (int ks = 0; ks < 2; ++ks)
            qfr[qs][ks] = *(const h8*)(qfh + (size_t)(n0 + qs * 16 + l15) * 64 + ks * 32 + quad * 8);

    fx4 acc[4][2];
    float lsum[4];
#pragma unroll
    for (int qs = 0; qs < 4; ++qs) {
#pragma unroll
        for (int ds = 0; ds < 2; ++ds) acc[qs][ds] = (fx4){0.f, 0.f, 0.f, 0.f};
        lsum[qs] = 0.f;
    }

    const int mbase = mh * MHALF;
    const fx4 z4 = {0.f, 0.f, 0.f, 0.f};

    float4 rt = *(const float4*)(tpg + mbase);   // prefetch topo tile 0

    for (int it = 0; it < MHALF / 32; ++it) {
        const int m0 = mbase + it * 32;
        const int cur = it & 1;

        // K/V fragments: issue BEFORE the barrier (global loads ride across
        // the lgkm-only barrier; no LDS dependency)
        h8 kfr[2][2];
#pragma unroll
        for (int ms = 0; ms < 2; ++ms)
#pragma unroll
            for (int ks = 0; ks < 2; ++ks)
                kfr[ms][ks] = *(const h8*)(kfh + (size_t)(m0 + ms * 16 + l15) * 64 + ks * 32 + quad * 8);
        h8 bV[2];
#pragma unroll
        for (int ds = 0; ds < 2; ++ds)
            bV[ds] = *(const h8*)(vTh + (size_t)(ds * 16 + l15) * Nn + m0 + quad * 8);

        // commit prefetched topo tile to LDS, issue next tile's load
        *(float4*)&tbuf[cur][trow][tcol4] = rt;
        if (it < MHALF / 32 - 1) rt = *(const float4*)(tpg + m0 + 32);
        // raw barrier: waits own LDS writes only; global loads stay in flight
        __asm__ volatile("s_waitcnt lgkmcnt(0)\n\ts_barrier" ::: "memory");

#pragma unroll
        for (int qs = 0; qs < 4; ++qs) {
            h2 pk[2][2];
#pragma unroll
            for (int ms = 0; ms < 2; ++ms) {
                // swapped: S2[row=m(quad*4+r)][col=q(l15)] = K @ Q^T
                fx4 tmp = __builtin_amdgcn_mfma_f32_16x16x32_f16(kfr[ms][0], qfr[qs][0], z4, 0, 0, 0);
                fx4 S2  = __builtin_amdgcn_mfma_f32_16x16x32_f16(kfr[ms][1], qfr[qs][1], tmp, 0, 0, 0);
                const fx4 tv = *(const fx4*)&tbuf[cur][qs * 16 + l15][ms * 16 + quad * 4];
                const float p0 = exp2f(fmaf(S2[0] * tv[0], QS_L2E, -SH_L2E));
                const float p1 = exp2f(fmaf(S2[1] * tv[1], QS_L2E, -SH_L2E));
                const float p2 = exp2f(fmaf(S2[2] * tv[2], QS_L2E, -SH_L2E));
                const float p3 = exp2f(fmaf(S2[3] * tv[3], QS_L2E, -SH_L2E));
                lsum[qs] += (p0 + p1) + (p2 + p3);
                pk[ms][0] = __builtin_bit_cast(h2, __builtin_amdgcn_cvt_pkrtz(p0, p1));
                pk[ms][1] = __builtin_bit_cast(h2, __builtin_amdgcn_cvt_pkrtz(p2, p3));
            }
            // PA fragment: lane's own 8 p-values in sigma-matched k-order
            union { h8 v; h2 p[4]; } pa;
            pa.p[0] = pk[0][0]; pa.p[1] = pk[0][1];
            pa.p[2] = pk[1][0]; pa.p[3] = pk[1][1];
#pragma unroll
            for (int ds = 0; ds < 2; ++ds)
                acc[qs][ds] = __builtin_amdgcn_mfma_f32_16x16x32_f16(pa.v, bV[ds], acc[qs][ds], 0, 0, 0);
        }
    }

    // epilogue: lsum lives at q=l15 per qs; reduce across the 4 quads
#pragma unroll
    for (int qs = 0; qs < 4; ++qs) {
        lsum[qs] += __shfl_xor(lsum[qs], 16);
        lsum[qs] += __shfl_xor(lsum[qs], 32);
    }

    float* paccm = pacc + (size_t)mh * Bn * Nn * Dn;
    float* plm   = pl   + (size_t)mh * Bn * Nn * Hn;
#pragma unroll
    for (int qs = 0; qs < 4; ++qs) {
#pragma unroll
        for (int r = 0; r < 4; ++r) {
            const size_t grow = (size_t)b * Nn + n0 + qs * 16 + quad * 4 + r;
            paccm[grow * Dn + h * HDn + l15]      = acc[qs][0][r];
            paccm[grow * Dn + h * HDn + 16 + l15] = acc[qs][1][r];
        }
        if (quad == 0)
            plm[((size_t)b * Nn + n0 + qs * 16 + l15) * Hn + h] = lsum[qs];
    }
}

// ---------------------------------------------------------------------------
// Kernel 3: merge + output projection as f16 MFMA GEMM (r17 rewrite).
//
// Old oproj: 1024 blocks each streaming all of Wo from L2 (268 MB, ~36us)
// + 512 broadcast ds_reads/thread. New: mirror proj's verified structure.
// grid (128,2) = 256 blocks (1/CU), 4 waves. Per ks-tile: load both pacc
// halves, merge + normalize by precomputed rcp(l) per head (head == ks for
// this col range), hi/lo-split ys to f16 (error ~2^-22: exact), B-fragments
// from WoT f16 (quantization ~2.4e-4 on out, vs 2e-3 current absmax,
// 7.07e-3 threshold). Wo L2 traffic 268 -> 67 MB; MFMA replaces FMA loop.
// C-tile mapping (row=w*16+quad*4+r, col=ct*16+l15) identical to proj's
// verified epilogue.
// ---------------------------------------------------------------------------
__global__ __launch_bounds__(256) void oproj_kernel(
    const float* __restrict__ pacc, const float* __restrict__ pl,
    const h1* __restrict__ WoT, const float* __restrict__ bo,
    float* __restrict__ out)
{
    const int tid = threadIdx.x;
    const int w = tid >> 6;
    const int lane = tid & 63;
    const int quad = lane >> 4;
    const int l15 = lane & 15;
    const int r0 = blockIdx.x * 64;
    const int hg = blockIdx.y;
    const int arow = r0 + w * 16 + l15;
    const size_t PACC = (size_t)Bn * Nn * Dn;
    const size_t PL = (size_t)Bn * Nn * Hn;

    // per-head reciprocal denominators for this thread's A-row
    float rl[8];
#pragma unroll
    for (int hh = 0; hh < 8; ++hh) {
        const float l = pl[(size_t)arow * Hn + hh] + pl[PL + (size_t)arow * Hn + hh];
        rl[hh] = __builtin_amdgcn_rcpf(l);
    }

    fx4 acc[8];
#pragma unroll
    for (int ct = 0; ct < 8; ++ct) acc[ct] = (fx4){0.f, 0.f, 0.f, 0.f};

    for (int ks = 0; ks < 8; ++ks) {
        // merge pacc halves, normalize (cols ks*32+quad*8.. all in head ks)
        float a0[8], a1[8];
        const size_t base = (size_t)arow * Dn + ks * 32 + quad * 8;
        *(float4*)&a0[0] = *(const float4*)&pacc[base];
        *(float4*)&a0[4] = *(const float4*)&pacc[base + 4];
        *(float4*)&a1[0] = *(const float4*)&pacc[PACC + base];
        *(float4*)&a1[4] = *(const float4*)&pacc[PACC + base + 4];
        h8 Ahi, Alo;
#pragma unroll
        for (int j = 0; j < 8; ++j) {
            const float yv = (a0[j] + a1[j]) * rl[ks];
            const h1 hi = (h1)yv;
            Ahi[j] = hi;
            Alo[j] = (h1)(yv - (float)hi);
        }
        h8 Bf[8];
#pragma unroll
        for (int ct = 0; ct < 8; ++ct)
            Bf[ct] = *(const h8*)&WoT[(size_t)(hg * 128 + ct * 16 + l15) * 256 + ks * 32 + quad * 8];
#pragma unroll
        for (int ct = 0; ct < 8; ++ct) {
            acc[ct] = __builtin_amdgcn_mfma_f32_16x16x32_f16(Ahi, Bf[ct], acc[ct], 0, 0, 0);
            acc[ct] = __builtin_amdgcn_mfma_f32_16x16x32_f16(Alo, Bf[ct], acc[ct], 0, 0, 0);
        }
    }

#pragma unroll
    for (int ct = 0; ct < 8; ++ct) {
        const int col = hg * 128 + ct * 16 + l15;
        const float bb = bo[col];
#pragma unroll
        for (int r = 0; r < 4; ++r)
            out[(size_t)(r0 + w * 16 + quad * 4 + r) * 256 + col] = acc[ct][r] + bb;
    }
}

// ---------------------------------------------------------------------------
extern "C" void kernel_launch(void* const* d_in, const int* in_sizes, int n_in,
                              void* d_out, int out_size, void* d_ws, size_t ws_size,
                              hipStream_t stream)
{
    const float* x    = (const float*)d_in[0];
    const float* topo = (const float*)d_in[1];
    const float* Wq   = (const float*)d_in[2];
    const float* bq   = (const float*)d_in[3];
    const float* Wk   = (const float*)d_in[4];
    const float* bk   = (const float*)d_in[5];
    const float* Wv   = (const float*)d_in[6];
    const float* bv   = (const float*)d_in[7];
    const float* Wo   = (const float*)d_in[8];
    const float* bo   = (const float*)d_in[9];
    float* out = (float*)d_out;

    char* ws = (char*)d_ws;
    const size_t MB = 1024 * 1024;
    h1* WT = (h1*)ws;                       // 4 x 64K h1 = 512 KB (q,k,v,o^T)
    h1* fq = (h1*)(ws + 1 * MB);
    h1* fk = (h1*)(ws + 9 * MB);
    h1* vT = (h1*)(ws + 17 * MB);
    float* pacc = (float*)(ws + 21 * MB);
    float* pl   = (float*)(ws + 37 * MB);

    cvtW_kernel<<<dim3(4, 4, 4), 256, 0, stream>>>(Wq, Wk, Wv, Wo, WT);
    proj_kernel<<<dim3(128, 6), 256, 0, stream>>>(x, WT, bq, bk, bv, fq, fk, vT);
    attn_kernel<<<dim3(Nn / NT, Bn, 2), 512, 0, stream>>>(fq, fk, vT, topo, pacc, pl);
    oproj_kernel<<<dim3(128, 2), 256, 0, stream>>>(pacc, pl, WT + 3 * 65536, bo, out);
}